// Round 2
// baseline (147.825 us; speedup 1.0000x reference)
//
#include <hip/hip_runtime.h>
#include <stdint.h>

#define DIMS 96
#define SEGS_PER_BLOCK 4
#define THREADS (DIMS * SEGS_PER_BLOCK)  // 384 threads = 6 waves

// Segment-mean aggregation over sorted seg_ids.
// Each 96-thread group owns one output segment (batch node); thread = one dim.
// Segment boundaries come from binary search on the sorted seg_ids array.
// NOTE: harness delivers integer inputs as int32 (NOT int64 per reference).
__global__ __launch_bounds__(THREADS) void seg_mean_concat_kernel(
    const float* __restrict__ emb,        // [N, 96]
    const float* __restrict__ self_feats, // [B, 96]
    const int*   __restrict__ nidx,       // [E] int32
    const int*   __restrict__ seg,        // [E] int32, sorted
    float* __restrict__ out,              // [B, 192]
    int B, int E)
{
    __shared__ int bounds[SEGS_PER_BLOCK + 1];

    const int b0 = blockIdx.x * SEGS_PER_BLOCK;
    const int tid = threadIdx.x;

    // Threads 0..SEGS_PER_BLOCK compute lower_bound(seg, b0 + t)
    if (tid <= SEGS_PER_BLOCK) {
        const int v = b0 + tid;
        int lo = 0, hi = E;
        while (lo < hi) {
            int mid = (lo + hi) >> 1;
            if (seg[mid] < v) lo = mid + 1; else hi = mid;
        }
        bounds[tid] = lo;
    }
    __syncthreads();

    const int g = tid / DIMS;        // segment group within block
    const int d = tid - g * DIMS;    // feature dim
    const int b = b0 + g;
    if (b >= B) return;

    const int start = bounds[g];
    const int end   = bounds[g + 1];

    float acc = 0.0f;
    int e = start;
    // 2-edge unroll for a bit of load ILP
    for (; e + 1 < end; e += 2) {
        const int j0 = nidx[e];
        const int j1 = nidx[e + 1];
        acc += emb[(long long)j0 * DIMS + d];
        acc += emb[(long long)j1 * DIMS + d];
    }
    if (e < end) {
        const int j = nidx[e];
        acc += emb[(long long)j * DIMS + d];
    }

    const int cnt = end - start;
    const float mean = acc / (float)(cnt > 0 ? cnt : 1);

    const long long orow = (long long)b * (2 * DIMS);
    out[orow + d]        = mean;
    out[orow + DIMS + d] = self_feats[(long long)b * DIMS + d] - mean;
}

extern "C" void kernel_launch(void* const* d_in, const int* in_sizes, int n_in,
                              void* d_out, int out_size, void* d_ws, size_t ws_size,
                              hipStream_t stream) {
    const float* emb        = (const float*)d_in[0];
    const float* self_feats = (const float*)d_in[1];
    const int*   nidx       = (const int*)d_in[2];
    const int*   seg        = (const int*)d_in[3];
    float*       out        = (float*)d_out;

    const int B = in_sizes[1] / DIMS;   // self_feats is [B, 96]
    const int E = in_sizes[2];          // neighbor_idx length

    const int grid = (B + SEGS_PER_BLOCK - 1) / SEGS_PER_BLOCK;
    hipLaunchKernelGGL(seg_mean_concat_kernel, dim3(grid), dim3(THREADS), 0, stream,
                       emb, self_feats, nidx, seg, out, B, E);
}

// Round 3
// 68.776 us; speedup vs baseline: 2.1494x; 2.1494x over previous
//
#include <hip/hip_runtime.h>
#include <stdint.h>

#define DIMS 96
#define VEC 4
#define LANES (DIMS / VEC)            // 24 lanes per segment, each owns a float4
#define SEGS_PER_BLOCK 16
#define THREADS (LANES * SEGS_PER_BLOCK)  // 384 threads = 6 waves

// Segment-mean aggregation over sorted seg_ids.
// 24-thread group per segment; each thread accumulates one float4 slice of the
// 96-dim row. 8-edge unroll keeps 8 independent dwordx4 gathers in flight to
// hide L2/HBM gather latency (round-2 profile: VALUBusy 12%, HBM 14% -> latency-bound).
// NOTE: harness delivers integer inputs as int32.
__global__ __launch_bounds__(THREADS) void seg_mean_concat_kernel(
    const float* __restrict__ emb,        // [N, 96]
    const float* __restrict__ self_feats, // [B, 96]
    const int*   __restrict__ nidx,       // [E] int32
    const int*   __restrict__ seg,        // [E] int32, sorted
    float* __restrict__ out,              // [B, 192]
    int B, int E)
{
    __shared__ int bounds[SEGS_PER_BLOCK + 1];

    const int b0 = blockIdx.x * SEGS_PER_BLOCK;
    const int tid = threadIdx.x;

    // Threads 0..SEGS_PER_BLOCK compute lower_bound(seg, b0 + t)
    if (tid <= SEGS_PER_BLOCK) {
        const int v = b0 + tid;
        int lo = 0, hi = E;
        while (lo < hi) {
            int mid = (lo + hi) >> 1;
            if (seg[mid] < v) lo = mid + 1; else hi = mid;
        }
        bounds[tid] = lo;
    }
    __syncthreads();

    const int g    = tid / LANES;      // segment group within block
    const int lane = tid - g * LANES;  // float4 slot within the row
    const int b    = b0 + g;
    if (b >= B) return;

    const int start = bounds[g];
    const int end   = bounds[g + 1];

    const float4* __restrict__ embv = (const float4*)emb;

    float4 acc = make_float4(0.f, 0.f, 0.f, 0.f);

    int e = start;
    // 8-edge unroll: 8 independent index loads, then 8 independent row gathers.
    for (; e + 8 <= end; e += 8) {
        const int j0 = nidx[e + 0];
        const int j1 = nidx[e + 1];
        const int j2 = nidx[e + 2];
        const int j3 = nidx[e + 3];
        const int j4 = nidx[e + 4];
        const int j5 = nidx[e + 5];
        const int j6 = nidx[e + 6];
        const int j7 = nidx[e + 7];
        const float4 v0 = embv[(size_t)j0 * LANES + lane];
        const float4 v1 = embv[(size_t)j1 * LANES + lane];
        const float4 v2 = embv[(size_t)j2 * LANES + lane];
        const float4 v3 = embv[(size_t)j3 * LANES + lane];
        const float4 v4 = embv[(size_t)j4 * LANES + lane];
        const float4 v5 = embv[(size_t)j5 * LANES + lane];
        const float4 v6 = embv[(size_t)j6 * LANES + lane];
        const float4 v7 = embv[(size_t)j7 * LANES + lane];
        acc.x += v0.x + v1.x + v2.x + v3.x + v4.x + v5.x + v6.x + v7.x;
        acc.y += v0.y + v1.y + v2.y + v3.y + v4.y + v5.y + v6.y + v7.y;
        acc.z += v0.z + v1.z + v2.z + v3.z + v4.z + v5.z + v6.z + v7.z;
        acc.w += v0.w + v1.w + v2.w + v3.w + v4.w + v5.w + v6.w + v7.w;
    }
    // Remainder
    for (; e < end; ++e) {
        const int j = nidx[e];
        const float4 v = embv[(size_t)j * LANES + lane];
        acc.x += v.x; acc.y += v.y; acc.z += v.z; acc.w += v.w;
    }

    const int cnt = end - start;
    const float inv = 1.0f / (float)(cnt > 0 ? cnt : 1);
    float4 mean;
    mean.x = acc.x * inv; mean.y = acc.y * inv;
    mean.z = acc.z * inv; mean.w = acc.w * inv;

    const float4 sf = *(const float4*)(self_feats + (size_t)b * DIMS + lane * VEC);
    float4 diff;
    diff.x = sf.x - mean.x; diff.y = sf.y - mean.y;
    diff.z = sf.z - mean.z; diff.w = sf.w - mean.w;

    float* orow = out + (size_t)b * (2 * DIMS);
    *(float4*)(orow + lane * VEC)        = mean;
    *(float4*)(orow + DIMS + lane * VEC) = diff;
}

extern "C" void kernel_launch(void* const* d_in, const int* in_sizes, int n_in,
                              void* d_out, int out_size, void* d_ws, size_t ws_size,
                              hipStream_t stream) {
    const float* emb        = (const float*)d_in[0];
    const float* self_feats = (const float*)d_in[1];
    const int*   nidx       = (const int*)d_in[2];
    const int*   seg        = (const int*)d_in[3];
    float*       out        = (float*)d_out;

    const int B = in_sizes[1] / DIMS;   // self_feats is [B, 96]
    const int E = in_sizes[2];          // neighbor_idx length

    const int grid = (B + SEGS_PER_BLOCK - 1) / SEGS_PER_BLOCK;
    hipLaunchKernelGGL(seg_mean_concat_kernel, dim3(grid), dim3(THREADS), 0, stream,
                       emb, self_feats, nidx, seg, out, B, E);
}